// Round 11
// baseline (111.751 us; speedup 1.0000x reference)
//
#include <hip/hip_runtime.h>

// CatNet_76553497084407 — SLAYER-style spiking CNN, fully collapsed over time.
//
// Only spike COUNTS flow between layers, so T=50 is never materialized.
// R10/R11: 2 blocks per sample (h-split, grid 512 x 512thr). Same 16 waves/CU,
// but TWO independent barrier domains per CU: when one block drains a
// __syncthreads, the other block's waves keep the VALU/LDS pipes fed
// (R3..R9 plateaued at ~41us with >50% stall at 1 block/CU).
// (R10 bench was an infra failure — container died; identical resubmit.)
// Phases 0-1 duplicated (cheap); conv2+pool split by p with 6-halo; conv3
// split by h; dense via one atomicAdd per block (2 addends -> bitwise
// deterministic; out zeroed by hipMemsetAsync in-stream).
// Kept: r1 even/odd split (conflict-free fused conv2 windows, R8a),
// guarded closed-form IF rate (R3), wave-uniform weight bases (scalar loads).
// R4-R6 lesson: no full-unrolled wide windows (VGPR cap -> scratch spill).

#define T_STEPS 50
#define THETA   0.9999f

__device__ __forceinline__ float spike_rate(float a) {
    constexpr float INV = 50.0f / 0.9999f;
    float t = a * INV;
    float c = fminf(fmaxf(floorf(t), 0.0f), 50.0f);
    // fall back to the exact 50-step f32 sim when t is near an integer
    bool risky = (t > 0.5f) && (fabsf(t - rintf(t)) < 5e-4f);
    if (__ballot(risky)) {
        float v = 0.f, cnt = 0.f;
#pragma unroll 1
        for (int k = 0; k < T_STEPS; ++k) {
            v += a;
            float s = (v >= THETA) ? 1.0f : 0.0f;
            v -= s * THETA;
            cnt += s;
        }
        c = cnt;
    }
    return c / 50.0f;   // true divide: match reference sum/T rounding
}

extern "C" __global__ void __launch_bounds__(512)
catnet_kernel(const float* __restrict__ x,
              const float* __restrict__ w1, const float* __restrict__ b1,
              const float* __restrict__ w2, const float* __restrict__ b2,
              const float* __restrict__ w3, const float* __restrict__ b3,
              const float* __restrict__ wf, const float* __restrict__ bf,
              float* __restrict__ out)
{
    const int bid  = blockIdx.x;
    const int n    = bid >> 1;
    const int s    = bid & 1;          // h-half of the sample
    const int tid  = threadIdx.x;
    const int wave = tid >> 6;
    const int lane = tid & 63;

    __shared__ float xbar[182];        // padded time-summed input
    __shared__ float r1e[16][91];      // r1 at even padded idx 2k
    __shared__ float r1o[16][91];      // r1 at odd  padded idx 2k+1
    __shared__ float r3p[32][89];      // [c][p+1], zero-padded borders
    __shared__ float r4s[32][83];      // only this block's h-range used

    // zero pads
    if (tid < 16)              { r1e[tid][0] = 0.f; r1o[tid][90] = 0.f; }
    if (tid >= 32 && tid < 64) { r3p[tid-32][0] = 0.f; r3p[tid-32][88] = 0.f; }
    if (tid == 64)             { xbar[0] = 0.f; xbar[181] = 0.f; }

    // ---- phase 0 (full range, duplicated): time-sum, 2 lanes per h ----
    const float* xn = x + (size_t)n * (180 * 50);
    if (tid < 360) {
        const int h = tid >> 1, q = tid & 1;
        const float2* row = (const float2*)(xn + h * 50);
        float sv = 0.f;
        for (int k = q; k < 25; k += 2) {
            float2 v = row[k];
            sv += v.x + v.y;
        }
        sv += __shfl_xor(sv, 1, 2);
        if (q == 0) xbar[h + 1] = sv;
    }
    __syncthreads();

    // ---- phase 1 (full range, duplicated): conv1 + rate -> r1e/r1o ----
    for (int idx = tid; idx < 16 * 180; idx += 512) {
        int c = idx / 180, h = idx - c * 180;
        float a = w1[c*3+0] * xbar[h] + w1[c*3+1] * xbar[h+1] + w1[c*3+2] * xbar[h+2];
        a = a / 50.0f + b1[c];
        float r = spike_rate(a);
        int pidx = h + 1;
        float* dst = (pidx & 1) ? &r1o[c][pidx >> 1] : &r1e[c][pidx >> 1];
        *dst = r;
    }
    __syncthreads();

    // ---- phase 2: conv2 + rate + pool(2)*1.1 + rate, split by p ----
    // 8 waves = 8 out-ch-groups(4); lanes -> pool output p (one pass).
    // s=0: p 0..46 ; s=1: p 41..86 (halo 41..46 computed by both, own LDS).
    {
        const int g    = __builtin_amdgcn_readfirstlane(wave);   // 0..7
        const int cntp = s ? 46 : 47;
        const int pbase= s ? 41 : 0;
        const bool act = lane < cntp;
        const int p    = pbase + (act ? lane : 0);
        const float* wb = w2 + g * 4 * 144;   // [j][ci][kh], j stride 144

        float a0[4], a1[4];
#pragma unroll
        for (int j = 0; j < 4; ++j) { a0[j] = b2[g*4 + j]; a1[j] = a0[j]; }

#pragma unroll 2
        for (int ci = 0; ci < 16; ++ci) {
            float we[5], wo[5];
#pragma unroll
            for (int d = 0; d < 5; ++d) {
                we[d] = r1e[ci][p + d];
                wo[d] = r1o[ci][p + d];
            }
#pragma unroll
            for (int j = 0; j < 4; ++j) {
                const float* wj = wb + j * 144 + ci * 9;
                // conv at h=2p (taps pidx 2p+kh) and h=2p+1, kh order preserved
                a0[j] += wj[0]*we[0] + wj[1]*wo[0] + wj[2]*we[1] + wj[3]*wo[1]
                       + wj[4]*we[2] + wj[5]*wo[2] + wj[6]*we[3] + wj[7]*wo[3]
                       + wj[8]*we[4];
                a1[j] += wj[0]*wo[0] + wj[1]*we[1] + wj[2]*wo[1] + wj[3]*we[2]
                       + wj[4]*wo[2] + wj[5]*we[3] + wj[6]*wo[3] + wj[7]*we[4]
                       + wj[8]*wo[4];
            }
        }
#pragma unroll
        for (int j = 0; j < 4; ++j) {
            float r20 = spike_rate(a0[j]);
            float r21 = spike_rate(a1[j]);
            float r3  = spike_rate(1.1f * (r20 + r21));
            if (act) r3p[g*4 + j][p + 1] = r3;
        }
    }
    __syncthreads();

    // ---- phase 4: conv3 (32->32, k=7, pad=1) + rate, split by h ----
    // 8 waves = 8 out-ch-groups(4); lanes -> h (one pass).
    // s=0: h 0..41 ; s=1: h 42..82.
    {
        const int g4   = __builtin_amdgcn_readfirstlane(wave) * 4;
        const int cnth = s ? 41 : 42;
        const int hbase= s ? 42 : 0;
        const bool act = lane < cnth;
        const int h0   = hbase + (act ? lane : 0);
        const float* wb = w3 + g4 * 224;      // [j][ci][kh], j stride 224

        float a[4];
#pragma unroll
        for (int j = 0; j < 4; ++j) a[j] = b3[g4 + j];

#pragma unroll 2
        for (int ci = 0; ci < 32; ++ci) {
            float rv[7];
#pragma unroll
            for (int kh = 0; kh < 7; ++kh) rv[kh] = r3p[ci][h0 + kh];
#pragma unroll
            for (int j = 0; j < 4; ++j) {
                const float* wj = wb + j * 224 + ci * 7;
#pragma unroll
                for (int kh = 0; kh < 7; ++kh)
                    a[j] += wj[kh] * rv[kh];
            }
        }
#pragma unroll
        for (int j = 0; j < 4; ++j) {
            float r = spike_rate(a[j]);
            if (act) r4s[g4 + j][h0] = r;
        }
    }
    __syncthreads();

    // ---- phase 5: partial dense over this block's h-range; atomicAdd ----
    // wave o<4 handles output o; lanes over h, loop over c.
    if (wave < 4) {
        const int o    = __builtin_amdgcn_readfirstlane(wave);
        const int cnth = s ? 41 : 42;
        const int hbase= s ? 42 : 0;
        const bool act = lane < cnth;
        const int hh   = hbase + (act ? lane : 0);
        float acc = 0.f;
        for (int c = 0; c < 32; ++c) {
            float rv = act ? r4s[c][hh] : 0.f;
            float wv = act ? wf[(o * 32 + c) * 83 + hh] : 0.f;
            acc += rv * wv;
        }
#pragma unroll
        for (int off = 32; off > 0; off >>= 1)
            acc += __shfl_down(acc, off, 64);
        if (lane == 0) {
            float contrib = s ? (acc + bf[o]) : acc;   // bf added exactly once
            atomicAdd(&out[n * 4 + o], contrib);        // 2 addends: a+b==b+a
        }
    }
}

extern "C" void kernel_launch(void* const* d_in, const int* in_sizes, int n_in,
                              void* d_out, int out_size, void* d_ws, size_t ws_size,
                              hipStream_t stream) {
    const float* x  = (const float*)d_in[0];
    const float* w1 = (const float*)d_in[1];
    const float* b1 = (const float*)d_in[2];
    const float* w2 = (const float*)d_in[3];
    const float* b2 = (const float*)d_in[4];
    const float* w3 = (const float*)d_in[5];
    const float* b3 = (const float*)d_in[6];
    const float* wf = (const float*)d_in[7];
    const float* bf = (const float*)d_in[8];
    float* outp = (float*)d_out;

    // d_out is re-poisoned to 0xAA before every timed launch; the dense
    // phase accumulates via atomicAdd, so zero it in-stream (graph-safe).
    hipMemsetAsync(outp, 0, (size_t)out_size * sizeof(float), stream);

    catnet_kernel<<<dim3(512), dim3(512), 0, stream>>>(
        x, w1, b1, w2, b2, w3, b3, wf, bf, outp);
}